// Round 1
// baseline (299.721 us; speedup 1.0000x reference)
//
#include <hip/hip_runtime.h>

typedef __attribute__((ext_vector_type(8))) short short8;
typedef __attribute__((ext_vector_type(4))) float float4v;
typedef __attribute__((ext_vector_type(4))) unsigned short us4;

#define DIN 128
#define NROWS 65536
#define SSIZE 1024
#define MLGK 256
#define DOUT 10
#define TM 128

__device__ inline unsigned short f2bf(float f) {
  unsigned int u = __float_as_uint(f);
  u = (u + 0x7FFFu + ((u >> 16) & 1u)) >> 16;
  return (unsigned short)u;
}
__device__ inline float bf2f(unsigned short h) {
  return __uint_as_float(((unsigned int)h) << 16);
}
// mish(x) = x*tanh(softplus(x)) = x*((1+e^x)^2-1)/((1+e^x)^2+1)
__device__ inline float mish_f(float x) {
  if (x > 30.f) return x;
  float e = __expf(x);
  float u = 1.f + e;
  float u2 = u * u;
  return x * (u2 - 1.f) / (u2 + 1.f);
}
// LDS element-index swizzle: breaks the D=128 row-major bank conflict (G4)
__device__ inline int swz(int row, int col) {
  return row * DIN + (col ^ ((row & 7) << 3));
}

// ---------- tiny precompute kernels (all fp32 math, negligible cost) ----------

__global__ __launch_bounds__(256) void k_prep(const float* __restrict__ W1,
                                              const float* __restrict__ W2,
                                              const float* __restrict__ Wc,
                                              unsigned short* W1b, unsigned short* W2b,
                                              unsigned short* Wcb) {
  int i = blockIdx.x * 256 + threadIdx.x;  // 49152 total
  if (i < 16384) {
    W1b[i] = f2bf(W1[i]);
  } else if (i < 32768) {
    W2b[i - 16384] = f2bf(W2[i - 16384]);
  } else {
    int j = i - 32768;              // [16][1024] padded Wc (rows >= DOUT are zero)
    int o = j >> 10;
    int s = j & 1023;
    Wcb[j] = (o < DOUT) ? f2bf(Wc[o * SSIZE + s]) : (unsigned short)0;
  }
}

__global__ __launch_bounds__(256) void k_anchor_tanh(const float* __restrict__ Wa,
                                                     const float* __restrict__ mlg,
                                                     float* anc_raw) {
  int i = blockIdx.x * 256 + threadIdx.x;  // 1024*128
  int s = i >> 7, d = i & 127;
  float acc = 0.f;
  for (int k = 0; k < MLGK; ++k) acc += Wa[s * MLGK + k] * mlg[k * DIN + d];
  anc_raw[i] = tanhf(acc);
}

__global__ __launch_bounds__(256) void k_encode(const float* __restrict__ in,
                                                const float* __restrict__ W,
                                                const float* __restrict__ b,
                                                float* out_f32, unsigned short* out_bf16) {
  int i = blockIdx.x * 256 + threadIdx.x;  // rows*128
  int r = i >> 7, d = i & 127;
  float acc = 0.f;
  for (int k = 0; k < DIN; ++k) acc += in[r * DIN + k] * W[d * DIN + k];
  float m = mish_f(acc + b[d]);
  if (out_f32) out_f32[i] = m;
  if (out_bf16) out_bf16[i] = f2bf(m);
}

__global__ __launch_bounds__(256) void k_a2(const unsigned short* __restrict__ ancb,
                                            float* a2) {
  int s = blockIdx.x * 256 + threadIdx.x;
  if (s >= SSIZE) return;
  float acc = 0.f;
  for (int d = 0; d < DIN; ++d) {
    float v = bf2f(ancb[s * DIN + d]);
    acc += v * v;
  }
  a2[s] = acc;
}

// ---------- the fused main kernel ----------
// Per block: 128 rows of x. encode(2 GEMMs+mish) -> per 128-anchor tile:
// distance MFMA -> sqrt -> logits MFMA accumulate -> log_softmax -> store.

__global__ __launch_bounds__(256) void k_main(
    const float* __restrict__ x, const float* __restrict__ b1,
    const float* __restrict__ b2, const float* __restrict__ bc,
    const unsigned short* __restrict__ W1b, const unsigned short* __restrict__ W2b,
    const unsigned short* __restrict__ Wcb, const unsigned short* __restrict__ ancb,
    const float* __restrict__ a2, float* __restrict__ out) {
  __shared__ __align__(16) unsigned short ldsA[TM * DIN];  // x tile, then x_dml
  __shared__ __align__(16) unsigned short ldsB[TM * DIN];  // hidden h
  __shared__ __align__(16) unsigned short ldsD[TM * 128];  // dist tile (bf16)
  __shared__ float x2s[TM];

  const int tid = threadIdx.x;
  const int wid = tid >> 6;        // 4 waves; wave owns rows [wid*32, wid*32+32)
  const int lane = tid & 63;
  const int l15 = lane & 15;
  const int lhi = lane >> 4;
  const int n0 = blockIdx.x * TM;

  // ---- stage x tile: global f32 -> bf16 -> swizzled LDS ----
  {
    const float* xg = x + (size_t)n0 * DIN;
    for (int i = tid; i < TM * 32; i += 256) {
      int row = i >> 5;
      int c4 = (i & 31) << 2;
      float4 v = *(const float4*)(xg + row * DIN + c4);
      us4 h;
      h[0] = f2bf(v.x); h[1] = f2bf(v.y); h[2] = f2bf(v.z); h[3] = f2bf(v.w);
      *(us4*)&ldsA[swz(row, c4)] = h;
    }
  }
  __syncthreads();

  // ---- encode layer (shared for both layers) ----
  // acc[rt][ct]: wave's 2 row-tiles x 8 col-tiles of 16x16 fragments
  auto encode_layer = [&](const unsigned short* __restrict__ Wb,
                          const float* __restrict__ bias,
                          const unsigned short* src, unsigned short* dst,
                          float* x2opt) {
    float4v acc[2][8];
#pragma unroll
    for (int rt = 0; rt < 2; ++rt)
#pragma unroll
      for (int ct = 0; ct < 8; ++ct) acc[rt][ct] = (float4v){0.f, 0.f, 0.f, 0.f};

#pragma unroll
    for (int kk = 0; kk < 4; ++kk) {
      short8 a[2];
#pragma unroll
      for (int rt = 0; rt < 2; ++rt) {
        int row = (wid * 2 + rt) * 16 + l15;
        int k = kk * 32 + lhi * 8;
        a[rt] = *(const short8*)&src[swz(row, k)];
      }
#pragma unroll
      for (int ct = 0; ct < 8; ++ct) {
        int col = ct * 16 + l15;
        short8 b = *(const short8*)&Wb[col * DIN + kk * 32 + lhi * 8];
        acc[0][ct] = __builtin_amdgcn_mfma_f32_16x16x32_bf16(a[0], b, acc[0][ct], 0, 0, 0);
        acc[1][ct] = __builtin_amdgcn_mfma_f32_16x16x32_bf16(a[1], b, acc[1][ct], 0, 0, 0);
      }
    }
    float sq[2][4];
#pragma unroll
    for (int rt = 0; rt < 2; ++rt)
#pragma unroll
      for (int j = 0; j < 4; ++j) sq[rt][j] = 0.f;
#pragma unroll
    for (int rt = 0; rt < 2; ++rt) {
#pragma unroll
      for (int ct = 0; ct < 8; ++ct) {
        int col = ct * 16 + l15;
        float bv = bias[col];
#pragma unroll
        for (int j = 0; j < 4; ++j) {
          int row = (wid * 2 + rt) * 16 + lhi * 4 + j;
          float m = mish_f(acc[rt][ct][j] + bv);
          unsigned short mb = f2bf(m);
          if (x2opt) {
            float mf = bf2f(mb);
            sq[rt][j] += mf * mf;  // square the *rounded* value for consistency
          }
          dst[swz(row, col)] = mb;
        }
      }
    }
    if (x2opt) {
#pragma unroll
      for (int rt = 0; rt < 2; ++rt)
#pragma unroll
        for (int j = 0; j < 4; ++j) {
          float s = sq[rt][j];
          s += __shfl_xor(s, 1, 16);
          s += __shfl_xor(s, 2, 16);
          s += __shfl_xor(s, 4, 16);
          s += __shfl_xor(s, 8, 16);
          if (l15 == 0) x2opt[(wid * 2 + rt) * 16 + lhi * 4 + j] = s;
        }
    }
  };

  encode_layer(W1b, b1, ldsA, ldsB, nullptr);   // h = mish(x@W1^T+b1)
  __syncthreads();
  encode_layer(W2b, b2, ldsB, ldsA, x2s);       // x_dml = mish(h@W2^T+b2), + row norms
  __syncthreads();

  // ---- distance + logits over 8 anchor tiles of 128 ----
  float4v lacc[2];
  lacc[0] = (float4v){0.f, 0.f, 0.f, 0.f};
  lacc[1] = (float4v){0.f, 0.f, 0.f, 0.f};

  for (int st = 0; st < 8; ++st) {
    float4v acc[2][8];
#pragma unroll
    for (int rt = 0; rt < 2; ++rt)
#pragma unroll
      for (int ct = 0; ct < 8; ++ct) acc[rt][ct] = (float4v){0.f, 0.f, 0.f, 0.f};

#pragma unroll
    for (int kk = 0; kk < 4; ++kk) {
      short8 a[2];
#pragma unroll
      for (int rt = 0; rt < 2; ++rt) {
        int row = (wid * 2 + rt) * 16 + l15;
        int k = kk * 32 + lhi * 8;
        a[rt] = *(const short8*)&ldsA[swz(row, k)];
      }
#pragma unroll
      for (int ct = 0; ct < 8; ++ct) {
        int sg = st * 128 + ct * 16 + l15;
        short8 b = *(const short8*)&ancb[sg * DIN + kk * 32 + lhi * 8];
        acc[0][ct] = __builtin_amdgcn_mfma_f32_16x16x32_bf16(a[0], b, acc[0][ct], 0, 0, 0);
        acc[1][ct] = __builtin_amdgcn_mfma_f32_16x16x32_bf16(a[1], b, acc[1][ct], 0, 0, 0);
      }
    }
    // dist = sqrt(max(x2 + a2 - 2*dot, 0)) -> bf16 -> LDS
#pragma unroll
    for (int rt = 0; rt < 2; ++rt) {
#pragma unroll
      for (int ct = 0; ct < 8; ++ct) {
        int sl = ct * 16 + l15;
        float a2v = a2[st * 128 + sl];
#pragma unroll
        for (int j = 0; j < 4; ++j) {
          int row = (wid * 2 + rt) * 16 + lhi * 4 + j;
          float sqv = x2s[row] + a2v - 2.f * acc[rt][ct][j];
          ldsD[swz(row, sl)] = f2bf(sqrtf(fmaxf(sqv, 0.f)));
        }
      }
    }
    __syncthreads();
    // logits += dist_tile @ Wc_tile^T  (B rows >= DOUT are zero-padded)
#pragma unroll
    for (int kk = 0; kk < 4; ++kk) {
      int k = kk * 32 + lhi * 8;
      short8 b = *(const short8*)&Wcb[l15 * SSIZE + st * 128 + k];
#pragma unroll
      for (int rt = 0; rt < 2; ++rt) {
        int row = (wid * 2 + rt) * 16 + l15;
        short8 a = *(const short8*)&ldsD[swz(row, k)];
        lacc[rt] = __builtin_amdgcn_mfma_f32_16x16x32_bf16(a, b, lacc[rt], 0, 0, 0);
      }
    }
    __syncthreads();  // before next iteration overwrites ldsD
  }

  // ---- bias + log_softmax (f32) + store ----
#pragma unroll
  for (int rt = 0; rt < 2; ++rt) {
#pragma unroll
    for (int j = 0; j < 4; ++j) {
      int row = (wid * 2 + rt) * 16 + lhi * 4 + j;
      int o = l15;
      float v = lacc[rt][j] + ((o < DOUT) ? bc[o] : 0.f);
      float mv = (o < DOUT) ? v : -1e30f;
      mv = fmaxf(mv, __shfl_xor(mv, 1, 16));
      mv = fmaxf(mv, __shfl_xor(mv, 2, 16));
      mv = fmaxf(mv, __shfl_xor(mv, 4, 16));
      mv = fmaxf(mv, __shfl_xor(mv, 8, 16));
      float ev = (o < DOUT) ? __expf(v - mv) : 0.f;
      float es = ev;
      es += __shfl_xor(es, 1, 16);
      es += __shfl_xor(es, 2, 16);
      es += __shfl_xor(es, 4, 16);
      es += __shfl_xor(es, 8, 16);
      float r = v - mv - logf(es);
      if (o < DOUT) out[(size_t)(n0 + row) * DOUT + o] = r;
    }
  }
}

extern "C" void kernel_launch(void* const* d_in, const int* in_sizes, int n_in,
                              void* d_out, int out_size, void* d_ws, size_t ws_size,
                              hipStream_t stream) {
  const float* x   = (const float*)d_in[0];
  const float* mlg = (const float*)d_in[1];
  const float* W1  = (const float*)d_in[2];
  const float* b1  = (const float*)d_in[3];
  const float* W2  = (const float*)d_in[4];
  const float* b2  = (const float*)d_in[5];
  const float* Wa  = (const float*)d_in[6];
  const float* Wc  = (const float*)d_in[7];
  const float* bc  = (const float*)d_in[8];
  float* out = (float*)d_out;

  // workspace layout (~1.41 MB total)
  unsigned short* W1b  = (unsigned short*)d_ws;        // 16384 bf16
  unsigned short* W2b  = W1b + 16384;                  // 16384 bf16
  unsigned short* Wcb  = W2b + 16384;                  // 16*1024 bf16 (zero-padded)
  unsigned short* ancb = Wcb + 16384;                  // 1024*128 bf16
  float* a2      = (float*)(ancb + SSIZE * DIN);       // 1024 f32
  float* anc_raw = a2 + SSIZE;                         // 1024*128 f32
  float* anc_h   = anc_raw + SSIZE * DIN;              // 1024*128 f32

  k_prep<<<192, 256, 0, stream>>>(W1, W2, Wc, W1b, W2b, Wcb);
  k_anchor_tanh<<<512, 256, 0, stream>>>(Wa, mlg, anc_raw);
  k_encode<<<512, 256, 0, stream>>>(anc_raw, W1, b1, anc_h, nullptr);
  k_encode<<<512, 256, 0, stream>>>(anc_h, W2, b2, nullptr, ancb);
  k_a2<<<4, 256, 0, stream>>>(ancb, a2);
  k_main<<<512, 256, 0, stream>>>(x, b1, b2, bc, W1b, W2b, Wcb, ancb, a2, out);
}

// Round 2
// 237.014 us; speedup vs baseline: 1.2646x; 1.2646x over previous
//
#include <hip/hip_runtime.h>

typedef __attribute__((ext_vector_type(8))) short short8;
typedef __attribute__((ext_vector_type(4))) float float4v;
typedef __attribute__((ext_vector_type(4))) unsigned short us4;

#define DIN 128
#define NROWS 65536
#define SSIZE 1024
#define MLGK 256
#define DOUT 10
#define TM 64   // rows per block; 4 waves x 16 rows

__device__ inline unsigned short f2bf(float f) {
  unsigned int u = __float_as_uint(f);
  u = (u + 0x7FFFu + ((u >> 16) & 1u)) >> 16;
  return (unsigned short)u;
}
__device__ inline float bf2f(unsigned short h) {
  return __uint_as_float(((unsigned int)h) << 16);
}
// mish(x) = x*tanh(softplus(x)) = x*((1+e^x)^2-1)/((1+e^x)^2+1)
__device__ inline float mish_f(float x) {
  if (x > 30.f) return x;
  float e = __expf(x);
  float u = 1.f + e;
  float u2 = u * u;
  return x * (u2 - 1.f) / (u2 + 1.f);
}
// LDS element-index swizzle: breaks the D=128 row-major bank conflict (G4)
__device__ inline int swz(int row, int col) {
  return row * DIN + (col ^ ((row & 7) << 3));
}

// ---------- tiny precompute kernels (all fp32 math, negligible cost) ----------

__global__ __launch_bounds__(256) void k_prep(const float* __restrict__ W1,
                                              const float* __restrict__ W2,
                                              const float* __restrict__ Wc,
                                              unsigned short* W1b, unsigned short* W2b,
                                              unsigned short* Wcb) {
  int i = blockIdx.x * 256 + threadIdx.x;  // 49152 total
  if (i < 16384) {
    W1b[i] = f2bf(W1[i]);
  } else if (i < 32768) {
    W2b[i - 16384] = f2bf(W2[i - 16384]);
  } else {
    int j = i - 32768;              // [16][1024] padded Wc (rows >= DOUT are zero)
    int o = j >> 10;
    int s = j & 1023;
    Wcb[j] = (o < DOUT) ? f2bf(Wc[o * SSIZE + s]) : (unsigned short)0;
  }
}

__global__ __launch_bounds__(256) void k_anchor_tanh(const float* __restrict__ Wa,
                                                     const float* __restrict__ mlg,
                                                     float* anc_raw) {
  int i = blockIdx.x * 256 + threadIdx.x;  // 1024*128
  int s = i >> 7, d = i & 127;
  float acc = 0.f;
  for (int k = 0; k < MLGK; ++k) acc += Wa[s * MLGK + k] * mlg[k * DIN + d];
  anc_raw[i] = tanhf(acc);
}

__global__ __launch_bounds__(256) void k_encode(const float* __restrict__ in,
                                                const float* __restrict__ W,
                                                const float* __restrict__ b,
                                                float* out_f32, unsigned short* out_bf16) {
  int i = blockIdx.x * 256 + threadIdx.x;  // rows*128
  int r = i >> 7, d = i & 127;
  float acc = 0.f;
  for (int k = 0; k < DIN; ++k) acc += in[r * DIN + k] * W[d * DIN + k];
  float m = mish_f(acc + b[d]);
  if (out_f32) out_f32[i] = m;
  if (out_bf16) out_bf16[i] = f2bf(m);
}

__global__ __launch_bounds__(256) void k_a2(const unsigned short* __restrict__ ancb,
                                            float* a2) {
  int s = blockIdx.x * 256 + threadIdx.x;
  if (s >= SSIZE) return;
  float acc = 0.f;
  for (int d = 0; d < DIN; ++d) {
    float v = bf2f(ancb[s * DIN + d]);
    acc += v * v;
  }
  a2[s] = acc;
}

// ---------- the fused main kernel ----------
// Per block: 64 rows of x, 4 waves x 16 rows. encode(2 GEMMs+mish) ->
// per 128-anchor tile: distance MFMA -> sqrt -> logits MFMA -> log_softmax.
// LDS ~33 KB -> 4 blocks/CU, 16 waves/CU (vs 1 block/4 waves before).

__global__ __launch_bounds__(256) void k_main(
    const float* __restrict__ x, const float* __restrict__ b1,
    const float* __restrict__ b2, const float* __restrict__ bc,
    const unsigned short* __restrict__ W1b, const unsigned short* __restrict__ W2b,
    const unsigned short* __restrict__ Wcb, const unsigned short* __restrict__ ancb,
    const float* __restrict__ a2, float* __restrict__ out) {
  __shared__ __align__(16) unsigned short ldsA[TM * DIN];  // x tile, then x_dml
  __shared__ __align__(16) unsigned short ldsB[TM * DIN];  // hidden h; later dist tile
  __shared__ float x2s[TM];

  const int tid = threadIdx.x;
  const int wid = tid >> 6;        // 4 waves; wave owns rows [wid*16, wid*16+16)
  const int lane = tid & 63;
  const int l15 = lane & 15;
  const int lhi = lane >> 4;
  const int n0 = blockIdx.x * TM;
  const int rbase = wid * 16;

  // ---- stage x tile: global f32 -> bf16 -> swizzled LDS ----
  {
    const float* xg = x + (size_t)n0 * DIN;
    for (int i = tid; i < TM * 32; i += 256) {
      int row = i >> 5;
      int c4 = (i & 31) << 2;
      float4 v = *(const float4*)(xg + row * DIN + c4);
      us4 h;
      h[0] = f2bf(v.x); h[1] = f2bf(v.y); h[2] = f2bf(v.z); h[3] = f2bf(v.w);
      *(us4*)&ldsA[swz(row, c4)] = h;
    }
  }
  __syncthreads();

  // ---- encode layer (shared for both layers); wave owns one 16-row tile ----
  auto encode_layer = [&](const unsigned short* __restrict__ Wb,
                          const float* __restrict__ bias,
                          const unsigned short* src, unsigned short* dst,
                          float* x2opt) {
    float4v acc[8];
#pragma unroll
    for (int ct = 0; ct < 8; ++ct) acc[ct] = (float4v){0.f, 0.f, 0.f, 0.f};

#pragma unroll
    for (int kk = 0; kk < 4; ++kk) {
      int k = kk * 32 + lhi * 8;
      short8 a = *(const short8*)&src[swz(rbase + l15, k)];
#pragma unroll
      for (int ct = 0; ct < 8; ++ct) {
        short8 b = *(const short8*)&Wb[(ct * 16 + l15) * DIN + k];
        acc[ct] = __builtin_amdgcn_mfma_f32_16x16x32_bf16(a, b, acc[ct], 0, 0, 0);
      }
    }
    float sq[4] = {0.f, 0.f, 0.f, 0.f};
#pragma unroll
    for (int ct = 0; ct < 8; ++ct) {
      int col = ct * 16 + l15;
      float bv = bias[col];
#pragma unroll
      for (int j = 0; j < 4; ++j) {
        int row = rbase + lhi * 4 + j;
        float m = mish_f(acc[ct][j] + bv);
        unsigned short mb = f2bf(m);
        if (x2opt) {
          float mf = bf2f(mb);
          sq[j] += mf * mf;  // square the *rounded* value for consistency
        }
        dst[swz(row, col)] = mb;
      }
    }
    if (x2opt) {
#pragma unroll
      for (int j = 0; j < 4; ++j) {
        float s = sq[j];
        s += __shfl_xor(s, 1, 16);
        s += __shfl_xor(s, 2, 16);
        s += __shfl_xor(s, 4, 16);
        s += __shfl_xor(s, 8, 16);
        if (l15 == 0) x2opt[rbase + lhi * 4 + j] = s;
      }
    }
  };

  encode_layer(W1b, b1, ldsA, ldsB, nullptr);   // h = mish(x@W1^T+b1)
  __syncthreads();
  encode_layer(W2b, b2, ldsB, ldsA, x2s);       // x_dml = mish(h@W2^T+b2), + row norms
  __syncthreads();

  // ---- distance + logits over 8 anchor tiles of 128 ----
  // ldsB is dead now; reuse it as the bf16 distance tile [TM][128].
  unsigned short* ldsD = ldsB;
  float4v lacc = (float4v){0.f, 0.f, 0.f, 0.f};

  for (int st = 0; st < 8; ++st) {
    float4v acc[8];
#pragma unroll
    for (int ct = 0; ct < 8; ++ct) acc[ct] = (float4v){0.f, 0.f, 0.f, 0.f};

#pragma unroll
    for (int kk = 0; kk < 4; ++kk) {
      int k = kk * 32 + lhi * 8;
      short8 a = *(const short8*)&ldsA[swz(rbase + l15, k)];
#pragma unroll
      for (int ct = 0; ct < 8; ++ct) {
        int sg = st * 128 + ct * 16 + l15;
        short8 b = *(const short8*)&ancb[sg * DIN + k];
        acc[ct] = __builtin_amdgcn_mfma_f32_16x16x32_bf16(a, b, acc[ct], 0, 0, 0);
      }
    }
    // dist = sqrt(max(x2 + a2 - 2*dot, 0)) -> bf16 -> LDS
#pragma unroll
    for (int ct = 0; ct < 8; ++ct) {
      int sl = ct * 16 + l15;
      float a2v = a2[st * 128 + sl];
#pragma unroll
      for (int j = 0; j < 4; ++j) {
        int row = rbase + lhi * 4 + j;
        float sqv = x2s[row] + a2v - 2.f * acc[ct][j];
        ldsD[swz(row, sl)] = f2bf(sqrtf(fmaxf(sqv, 0.f)));
      }
    }
    __syncthreads();
    // logits += dist_tile @ Wc_tile^T  (B rows >= DOUT are zero-padded)
#pragma unroll
    for (int kk = 0; kk < 4; ++kk) {
      int k = kk * 32 + lhi * 8;
      short8 b = *(const short8*)&Wcb[l15 * SSIZE + st * 128 + k];
      short8 a = *(const short8*)&ldsD[swz(rbase + l15, k)];
      lacc = __builtin_amdgcn_mfma_f32_16x16x32_bf16(a, b, lacc, 0, 0, 0);
    }
    __syncthreads();  // before next iteration overwrites ldsD
  }

  // ---- bias + log_softmax (f32) + store ----
#pragma unroll
  for (int j = 0; j < 4; ++j) {
    int row = rbase + lhi * 4 + j;
    int o = l15;
    float v = lacc[j] + ((o < DOUT) ? bc[o] : 0.f);
    float mv = (o < DOUT) ? v : -1e30f;
    mv = fmaxf(mv, __shfl_xor(mv, 1, 16));
    mv = fmaxf(mv, __shfl_xor(mv, 2, 16));
    mv = fmaxf(mv, __shfl_xor(mv, 4, 16));
    mv = fmaxf(mv, __shfl_xor(mv, 8, 16));
    float ev = (o < DOUT) ? __expf(v - mv) : 0.f;
    float es = ev;
    es += __shfl_xor(es, 1, 16);
    es += __shfl_xor(es, 2, 16);
    es += __shfl_xor(es, 4, 16);
    es += __shfl_xor(es, 8, 16);
    float r = v - mv - logf(es);
    if (o < DOUT) out[(size_t)(n0 + row) * DOUT + o] = r;
  }
}

extern "C" void kernel_launch(void* const* d_in, const int* in_sizes, int n_in,
                              void* d_out, int out_size, void* d_ws, size_t ws_size,
                              hipStream_t stream) {
  const float* x   = (const float*)d_in[0];
  const float* mlg = (const float*)d_in[1];
  const float* W1  = (const float*)d_in[2];
  const float* b1  = (const float*)d_in[3];
  const float* W2  = (const float*)d_in[4];
  const float* b2  = (const float*)d_in[5];
  const float* Wa  = (const float*)d_in[6];
  const float* Wc  = (const float*)d_in[7];
  const float* bc  = (const float*)d_in[8];
  float* out = (float*)d_out;

  // workspace layout (~1.41 MB total)
  unsigned short* W1b  = (unsigned short*)d_ws;        // 16384 bf16
  unsigned short* W2b  = W1b + 16384;                  // 16384 bf16
  unsigned short* Wcb  = W2b + 16384;                  // 16*1024 bf16 (zero-padded)
  unsigned short* ancb = Wcb + 16384;                  // 1024*128 bf16
  float* a2      = (float*)(ancb + SSIZE * DIN);       // 1024 f32
  float* anc_raw = a2 + SSIZE;                         // 1024*128 f32
  float* anc_h   = anc_raw + SSIZE * DIN;              // 1024*128 f32

  k_prep<<<192, 256, 0, stream>>>(W1, W2, Wc, W1b, W2b, Wcb);
  k_anchor_tanh<<<512, 256, 0, stream>>>(Wa, mlg, anc_raw);
  k_encode<<<512, 256, 0, stream>>>(anc_raw, W1, b1, anc_h, nullptr);
  k_encode<<<512, 256, 0, stream>>>(anc_h, W2, b2, nullptr, ancb);
  k_a2<<<4, 256, 0, stream>>>(ancb, a2);
  k_main<<<1024, 256, 0, stream>>>(x, b1, b2, bc, W1b, W2b, Wcb, ancb, a2, out);
}